// Round 2
// baseline (254.148 us; speedup 1.0000x reference)
//
#include <hip/hip_runtime.h>
#include <hip/hip_bf16.h>

#define NQ 2048
#define NB 2

typedef unsigned short u16;
typedef unsigned int u32;
typedef _Float16 f16;
typedef __attribute__((ext_vector_type(8))) _Float16 half8;
typedef __attribute__((ext_vector_type(2))) __fp16 fp16x2;
typedef __attribute__((ext_vector_type(4))) float f32x4;
typedef __attribute__((ext_vector_type(2))) unsigned int u32x2;

#define MFMAH(A, B, C) __builtin_amdgcn_mfma_f32_16x16x32_f16(A, B, C, 0, 0, 0)

__device__ __forceinline__ u16 f2h(float x) {
    f16 h = (f16)x;                 // v_cvt_f16_f32 (RNE)
    return *(u16*)&h;
}
// packed f32x2 -> fp16x2 (v_cvt_pkrtz_f16_f32), returned as u32
__device__ __forceinline__ u32 pk_h2(float a, float b) {
    union { fp16x2 v; u32 u; } c;
    c.v = __builtin_amdgcn_cvt_pkrtz(a, b);
    return c.u;
}
// raw v_exp_f32 (2^x)
__device__ __forceinline__ float fexp2(float x) {
#if __has_builtin(__builtin_amdgcn_exp2f)
    return __builtin_amdgcn_exp2f(x);
#else
    return exp2f(x);
#endif
}
// async global->LDS DMA, 16B/lane; lds dest is wave-uniform base + lane*16
__device__ __forceinline__ void glds16(const u16* g, u16* l) {
    typedef const __attribute__((address_space(1))) u16 gu16;
    typedef __attribute__((address_space(3))) u16 lu16;
    __builtin_amdgcn_global_load_lds((gu16*)g, (lu16*)l, 16, 0, 0);
}
// VALU cross-lane swaps (gfx950): a/b both updated.
// pl32: a' = [a.lo32, b.lo32], b' = [a.hi32, b.hi32]
__device__ __forceinline__ void pl32swap(u32& a, u32& b) {
#if __has_builtin(__builtin_amdgcn_permlane32_swap)
    u32x2 r = __builtin_amdgcn_permlane32_swap(a, b, false, false);
    a = r[0]; b = r[1];
#else
    asm volatile("v_permlane32_swap_b32 %0, %1" : "+v"(a), "+v"(b));
#endif
}
// pl16: a' = [a.q0, b.q0, a.q2, b.q2], b' = [a.q1, b.q1, a.q3, b.q3]  (q = 16-lane row)
__device__ __forceinline__ void pl16swap(u32& a, u32& b) {
#if __has_builtin(__builtin_amdgcn_permlane16_swap)
    u32x2 r = __builtin_amdgcn_permlane16_swap(a, b, false, false);
    a = r[0]; b = r[1];
#else
    asm volatile("v_permlane16_swap_b32 %0, %1" : "+v"(a), "+v"(b));
#endif
}

// q-scale: 1/sqrt(64) * log2(e), so attention scores land in log2 domain
#define QSCALE 0.18033688011112042f

// ============ merge to fp16: rows 0..3071 = q,k,v; 3072..4095 = o ============
// vectorized x4: one block = one 1024-col row, float4 loads, ushort4 store
__global__ __launch_bounds__(256) void merge_w16(
    const float* __restrict__ w0, const float* __restrict__ dw0, const float* __restrict__ db0,
    const float* __restrict__ w1, const float* __restrict__ dw1, const float* __restrict__ db1,
    const float* __restrict__ w2, const float* __restrict__ dw2, const float* __restrict__ db2,
    const float* __restrict__ w3, const float* __restrict__ dw3, const float* __restrict__ db3,
    u16* __restrict__ Wf) {
    int i4 = (blockIdx.x * 256 + threadIdx.x) * 4;   // over 4096*1024
    int row = i4 >> 10, col = i4 & 1023;
    int which = row >> 10, lr = row & 1023;
    const float* W  = (which == 0) ? w0  : (which == 1) ? w1  : (which == 2) ? w2  : w3;
    const float* dW = (which == 0) ? dw0 : (which == 1) ? dw1 : (which == 2) ? dw2 : dw3;
    const float* dB = (which == 0) ? db0 : (which == 1) ? db1 : (which == 2) ? db2 : db3;
    float4 acc = *(const float4*)&W[lr * 1024 + col];
#pragma unroll
    for (int r = 0; r < 5; ++r) {
        float s = dB[lr * 5 + r];                    // block-uniform
        float4 w4 = *(const float4*)&dW[r * 1024 + col];
        acc.x += s * w4.x; acc.y += s * w4.y;
        acc.z += s * w4.z; acc.w += s * w4.w;
    }
    if (which == 0) { acc.x *= QSCALE; acc.y *= QSCALE; acc.z *= QSCALE; acc.w *= QSCALE; }
    ushort4 o = make_ushort4(f2h(acc.x), f2h(acc.y), f2h(acc.z), f2h(acc.w));
    *(ushort4*)&Wf[i4] = o;
}

__global__ __launch_bounds__(256) void bias_pack(
    const float* __restrict__ b0, const float* __restrict__ b1,
    const float* __restrict__ b2, const float* __restrict__ b3,
    float* __restrict__ ball) {
    int t = blockIdx.x * 256 + threadIdx.x;   // 4096
    int which = t >> 10;
    const float* B = (which == 0) ? b0 : (which == 1) ? b1 : (which == 2) ? b2 : b3;
    float v = B[t & 1023];
    if (which == 0) v *= QSCALE;
    ball[t] = v;
}

// x -> single fp16 (RNE)
__global__ __launch_bounds__(256) void xcast(const float* __restrict__ x,
                                             u16* __restrict__ xf) {
    int i4 = (blockIdx.x * 256 + threadIdx.x) * 4;
    float4 v = *(const float4*)&x[i4];
    *(uint2*)&xf[i4] = make_uint2(pk_h2(v.x, v.y), pk_h2(v.z, v.w));
}

// ============ fp16 GEMM: C[4096][N] = A @ B^T + bias ============
// Single fp16 product. TM x 128 tile, BK=64 staged as two 32-col halves
// (each half keeps the packed [row][32] m97 bank layout), global_load_lds(16).
// If VtOut: column blocks bn >= 2048 (V third of fused QKV) store TRANSPOSED
// to VtOut[(col-2048)][4096].
template <int TM>
__global__ __launch_bounds__(256) void gemm_f16(
    const u16* __restrict__ Af, const u16* __restrict__ Bf,
    const float* __restrict__ bias,
    float* __restrict__ Cf, u16* __restrict__ Cb, int ldc,
    u16* __restrict__ VtOut) {
    constexpr int MI = TM / 32;               // m-subtiles per wave
    __shared__ u16 As[2][TM * 32];
    __shared__ u16 Bs[2][128 * 32];
    const int tid = threadIdx.x;
    const int wid = tid >> 6, lane = tid & 63;
    const int ln = lane & 15, quad = lane >> 4;
    const int bm = blockIdx.y * TM, bn = blockIdx.x * 128;
    const int wm = (wid >> 1) * (TM / 2), wn = (wid & 1) * 64;
    const int lrow = lane >> 2;               // DMA: row within 16-row group
    const int lchunk = (lane & 3) * 8;        // DMA: u16 offset of 16B chunk

    f32x4 acc[MI][4];
#pragma unroll
    for (int i = 0; i < MI; ++i)
#pragma unroll
        for (int j = 0; j < 4; ++j) acc[i][j] = (f32x4){0.f, 0.f, 0.f, 0.f};

    for (int k0 = 0; k0 < 1024; k0 += 64) {
#pragma unroll
        for (int hf = 0; hf < 2; ++hf) {
#pragma unroll
            for (int p = 0; p < TM / 64; ++p) {
                int r = p * 64 + wid * 16;
                glds16(&Af[(bm + r + lrow) * 1024 + k0 + hf * 32 + lchunk],
                       &As[hf][r * 32]);
            }
#pragma unroll
            for (int p = 0; p < 2; ++p) {
                int r = p * 64 + wid * 16;
                glds16(&Bf[(bn + r + lrow) * 1024 + k0 + hf * 32 + lchunk],
                       &Bs[hf][r * 32]);
            }
        }
        asm volatile("s_waitcnt vmcnt(0)" ::: "memory");
        __syncthreads();

        half8 a[MI][2], b[4][2];
#pragma unroll
        for (int kc = 0; kc < 2; ++kc) {
#pragma unroll
            for (int j = 0; j < 4; ++j)
                b[j][kc] = *(const half8*)&Bs[kc][(wn + j * 16 + ln) * 32 + quad * 8];
#pragma unroll
            for (int i = 0; i < MI; ++i)
                a[i][kc] = *(const half8*)&As[kc][(wm + i * 16 + ln) * 32 + quad * 8];
        }
#pragma unroll
        for (int i = 0; i < MI; ++i)
#pragma unroll
            for (int j = 0; j < 4; ++j) {
                acc[i][j] = MFMAH(a[i][0], b[j][0], acc[i][j]);
                acc[i][j] = MFMAH(a[i][1], b[j][1], acc[i][j]);
            }
        __syncthreads();
    }

    if (VtOut && bn >= 2048) {
        // transposed store: VtOut[d][seq]; lane holds 4 consecutive seq rows.
#pragma unroll
        for (int i = 0; i < MI; ++i)
#pragma unroll
            for (int j = 0; j < 4; ++j) {
                int col = bn + wn + j * 16 + ln;
                float bv = bias[col];
                int colV = col - 2048;
                int row0 = bm + wm + i * 16 + quad * 4;
                ushort4 pk = make_ushort4(f2h(acc[i][j][0] + bv), f2h(acc[i][j][1] + bv),
                                          f2h(acc[i][j][2] + bv), f2h(acc[i][j][3] + bv));
                *(ushort4*)&VtOut[colV * 4096 + row0] = pk;
            }
        return;
    }

#pragma unroll
    for (int i = 0; i < MI; ++i)
#pragma unroll
        for (int j = 0; j < 4; ++j) {
            int col = bn + wn + j * 16 + ln;
            float bv = bias[col];
#pragma unroll
            for (int r = 0; r < 4; ++r) {
                int row = bm + wm + i * 16 + quad * 4 + r;
                float v = acc[i][j][r] + bv;
                if (Cb) Cb[row * ldc + col] = f2h(v);
                else    Cf[row * ldc + col] = v;
            }
        }
}

// ============ flash attention, fp16 MFMA, transposed S/O ============
// Block: 4 waves x 32 q-rows = 128 q of one (b,h). 64-key tiles.
// K staged via glds16 into packed [key][32]-per-half layout with XOR chunk
// swizzle (phys 16B chunk = logical ^ ((row>>1)&3)), applied BOTH sides:
// pre-swizzled global source on the DMA, swizzled address on ds_read ->
// per-phase bank spread is 2-way (free). V fragments are loaded DIRECTLY
// from global (Vt rows are contiguous 16B per lane) - no Vs LDS, no V bank
// conflicts, V traffic rides the idle VMEM pipe and is L1-shared across the
// 4 waves of the block. One vmcnt(0)+barrier per tile (K double buffer).
// Scores in log2 domain -> p = v_exp_f32 raw. S->P transform in-register:
// cvt_pkrtz + permlane32/16 butterfly. Row sums via ones-MFMA.
__global__ __launch_bounds__(256) void flash_f16(
    const u16* __restrict__ QKV, const u16* __restrict__ Vt,
    u16* __restrict__ AO) {
    __shared__ u16 Ks[2][2][64 * 32];   // [buf][d-half][key row][32], chunk-swizzled

    const int tid = threadIdx.x;
    const int wid = tid >> 6, lane = tid & 63;
    const int ln = lane & 15, quad = lane >> 4;
    const int qt = blockIdx.x, h = blockIdx.y, b = blockIdx.z;
    const int rowbase = b * NQ;
    const int col0 = h * 64;
    const int q0 = rowbase + qt * 128 + wid * 32;
    const int lrow = lane >> 2;          // DMA: row within 16-row group
    // DMA source chunk (pre-swizzle): lane l fetches logical chunk (l&3)^((lrow>>1)&3)
    const int kchunk = ((lane & 3) ^ ((lrow >> 1) & 3)) * 8;
    // fragment-read physical chunk: quad ^ ((row>>1)&3), row&15 == ln
    const int kswz = (quad ^ ((ln >> 1) & 3)) * 8;

    const half8 ones = {(f16)1, (f16)1, (f16)1, (f16)1,
                        (f16)1, (f16)1, (f16)1, (f16)1};

    // Q fragments (B-operand: lane ln = q-row q0+mi*16+ln, k = kc*32+quad*8+j)
    half8 qf[2][2];
#pragma unroll
    for (int mi = 0; mi < 2; ++mi)
#pragma unroll
        for (int kc = 0; kc < 2; ++kc)
            qf[mi][kc] = *(const half8*)&QKV[(q0 + mi * 16 + ln) * 3072 + col0 +
                                             kc * 32 + quad * 8];

    f32x4 accO[4][2];    // [a: d-subtile][mi], element (d=a*16+quad*4+r, q=mi*16+ln)
    f32x4 accS[2];       // row sums, col = q = ln
#pragma unroll
    for (int mi = 0; mi < 2; ++mi) {
        accS[mi] = (f32x4){0.f, 0.f, 0.f, 0.f};
#pragma unroll
        for (int a = 0; a < 4; ++a) accO[a][mi] = (f32x4){0.f, 0.f, 0.f, 0.f};
    }

    const int NT = NQ / 64;
    // K DMA per-lane global base (16 rows x 64B per glds16 call per wave)
    const u16* Kg = QKV + (rowbase + wid * 16 + lrow) * 3072 + 1024 + col0 + kchunk;
    // V fragment direct-load base: element (d = col0+a*16+ln, seq = kt*64+hf*32+quad*8+j)
    const u16* Vg = Vt + (col0 + ln) * 4096 + rowbase + quad * 8;

#define STAGEK(kt2, bu)                                        \
    {                                                          \
        const u16* kg_ = Kg + (kt2) * (64 * 3072);             \
        glds16(kg_,      &Ks[bu][0][wid * 512]);               \
        glds16(kg_ + 32, &Ks[bu][1][wid * 512]);               \
    }

    STAGEK(0, 0);
    asm volatile("s_waitcnt vmcnt(0)" ::: "memory");
    __syncthreads();

#pragma unroll 2
    for (int kt = 0; kt < NT; ++kt) {
        const int cur = kt & 1;
        if (kt + 1 < NT) STAGEK(kt + 1, cur ^ 1);   // DMA overlaps this tile's compute

        // V fragments for this tile: direct global loads, consumed after exp
        half8 vf[4][2];
#pragma unroll
        for (int a = 0; a < 4; ++a)
#pragma unroll
            for (int hf = 0; hf < 2; ++hf)
                vf[a][hf] = *(const half8*)&Vg[a * 16 * 4096 + kt * 64 + hf * 32];

        // S^T = K @ Q^T : element (key = a*16+quad*4+r, q = mi*16+ln)
        f32x4 s[4][2];
#pragma unroll
        for (int a = 0; a < 4; ++a) {
            half8 kf0 = *(const half8*)&Ks[cur][0][(a * 16 + ln) * 32 + kswz];
            half8 kf1 = *(const half8*)&Ks[cur][1][(a * 16 + ln) * 32 + kswz];
#pragma unroll
            for (int mi = 0; mi < 2; ++mi) {
                f32x4 t = (f32x4){0.f, 0.f, 0.f, 0.f};
                t = MFMAH(kf0, qf[mi][0], t);
                t = MFMAH(kf1, qf[mi][1], t);
                s[a][mi] = t;
            }
        }

        // p = 2^s, pack to fp16 pairs, then register butterfly to B-operand
        // layout: pf[mi][kc] element j = P[key = kc*32 + quad*8 + j][q = mi*16+ln].
        half8 pf[2][2];
#pragma unroll
        for (int mi = 0; mi < 2; ++mi)
#pragma unroll
            for (int kc = 0; kc < 2; ++kc) {
                u32 c0 = pk_h2(fexp2(s[2 * kc][mi][0]), fexp2(s[2 * kc][mi][1]));
                u32 c1 = pk_h2(fexp2(s[2 * kc][mi][2]), fexp2(s[2 * kc][mi][3]));
                u32 c2 = pk_h2(fexp2(s[2 * kc + 1][mi][0]), fexp2(s[2 * kc + 1][mi][1]));
                u32 c3 = pk_h2(fexp2(s[2 * kc + 1][mi][2]), fexp2(s[2 * kc + 1][mi][3]));
                pl32swap(c0, c2);
                pl32swap(c1, c3);
                pl16swap(c0, c2);
                pl16swap(c1, c3);
                union { u32 u[4]; half8 h; } pu;
                pu.u[0] = c0; pu.u[1] = c1; pu.u[2] = c2; pu.u[3] = c3;
                pf[mi][kc] = pu.h;
                accS[mi] = MFMAH(ones, pf[mi][kc], accS[mi]);   // row sums
            }

        // O^T += V^T @ P^T : element (d = a*16+quad*4+r, q = mi*16+ln)
#pragma unroll
        for (int a = 0; a < 4; ++a) {
#pragma unroll
            for (int mi = 0; mi < 2; ++mi) {
                accO[a][mi] = MFMAH(vf[a][0], pf[mi][0], accO[a][mi]);
                accO[a][mi] = MFMAH(vf[a][1], pf[mi][1], accO[a][mi]);
            }
        }

        asm volatile("s_waitcnt vmcnt(0)" ::: "memory");   // next K tile landed
        __syncthreads();                                   // all waves done with cur
    }
#undef STAGEK

    // epilogue: normalize (inv uniform per lane), single fp16 AO, ushort4 stores
#pragma unroll
    for (int mi = 0; mi < 2; ++mi) {
        float inv = 1.f / accS[mi][0];
        int q = q0 + mi * 16 + ln;
#pragma unroll
        for (int a = 0; a < 4; ++a) {
            ushort4 pk = make_ushort4(f2h(accO[a][mi][0] * inv),
                                      f2h(accO[a][mi][1] * inv),
                                      f2h(accO[a][mi][2] * inv),
                                      f2h(accO[a][mi][3] * inv));
            *(ushort4*)&AO[q * 1024 + col0 + a * 16 + quad * 4] = pk;
        }
    }
}

// ============ launch ============
extern "C" void kernel_launch(void* const* d_in, const int* in_sizes, int n_in,
                              void* d_out, int out_size, void* d_ws, size_t ws_size,
                              hipStream_t stream) {
    const float* x = (const float*)d_in[0];
    const float* w[4]  = {(const float*)d_in[1],  (const float*)d_in[5],
                          (const float*)d_in[9],  (const float*)d_in[13]};
    const float* bv[4] = {(const float*)d_in[2],  (const float*)d_in[6],
                          (const float*)d_in[10], (const float*)d_in[14]};
    const float* dw[4] = {(const float*)d_in[3],  (const float*)d_in[7],
                          (const float*)d_in[11], (const float*)d_in[15]};
    const float* db[4] = {(const float*)d_in[4],  (const float*)d_in[8],
                          (const float*)d_in[12], (const float*)d_in[16]};

    u16* p = (u16*)d_ws;
    u16* Wf  = p; p += 4096 * 1024;
    u16* xf  = p; p += 4096 * 1024;
    u16* QKV = p; p += 4096 * 3072;   // V third unused (lives in Vt)
    u16* Vt  = p; p += 1024 * 4096;
    float* ball = (float*)p;          // 4096 floats
    // AO aliases xf: x is dead after the QKV GEMM completes (same stream).
    u16* AO = xf;

    merge_w16<<<4096, 256, 0, stream>>>(w[0], dw[0], db[0], w[1], dw[1], db[1],
                                        w[2], dw[2], db[2], w[3], dw[3], db[3], Wf);
    bias_pack<<<16, 256, 0, stream>>>(bv[0], bv[1], bv[2], bv[3], ball);
    xcast<<<4096, 256, 0, stream>>>(x, xf);

    // fused q,k,v projection: q,k -> QKV fp16 row-major; v -> Vt transposed
    gemm_f16<128><<<dim3(24, 32), 256, 0, stream>>>(xf, Wf, ball,
                                                    nullptr, QKV, 3072, Vt);

    flash_f16<<<dim3(NQ / 128, 16, NB), 256, 0, stream>>>(QKV, Vt, AO);

    // o projection: fp32 out, TM=64 -> 512 blocks (2 blocks/CU)
    gemm_f16<64><<<dim3(8, 64), 256, 0, stream>>>(AO, Wf + 3072 * 1024,
                                                  ball + 3072, (float*)d_out, nullptr, 1024,
                                                  nullptr);
}

// Round 3
// 253.894 us; speedup vs baseline: 1.0010x; 1.0010x over previous
//
#include <hip/hip_runtime.h>
#include <hip/hip_bf16.h>

#define NQ 2048
#define NB 2

typedef unsigned short u16;
typedef unsigned int u32;
typedef _Float16 f16;
typedef __attribute__((ext_vector_type(8))) _Float16 half8;
typedef __attribute__((ext_vector_type(2))) __fp16 fp16x2;
typedef __attribute__((ext_vector_type(4))) float f32x4;
typedef __attribute__((ext_vector_type(2))) unsigned int u32x2;

#define MFMAH(A, B, C) __builtin_amdgcn_mfma_f32_16x16x32_f16(A, B, C, 0, 0, 0)

__device__ __forceinline__ u16 f2h(float x) {
    f16 h = (f16)x;                 // v_cvt_f16_f32 (RNE)
    return *(u16*)&h;
}
// packed f32x2 -> fp16x2 (v_cvt_pkrtz_f16_f32), returned as u32
__device__ __forceinline__ u32 pk_h2(float a, float b) {
    union { fp16x2 v; u32 u; } c;
    c.v = __builtin_amdgcn_cvt_pkrtz(a, b);
    return c.u;
}
// raw v_exp_f32 (2^x)
__device__ __forceinline__ float fexp2(float x) {
#if __has_builtin(__builtin_amdgcn_exp2f)
    return __builtin_amdgcn_exp2f(x);
#else
    return exp2f(x);
#endif
}
// async global->LDS DMA, 16B/lane; lds dest is wave-uniform base + lane*16
__device__ __forceinline__ void glds16(const u16* g, u16* l) {
    typedef const __attribute__((address_space(1))) u16 gu16;
    typedef __attribute__((address_space(3))) u16 lu16;
    __builtin_amdgcn_global_load_lds((gu16*)g, (lu16*)l, 16, 0, 0);
}
// VALU cross-lane swaps (gfx950): a/b both updated.
// pl32: a' = [a.lo32, b.lo32], b' = [a.hi32, b.hi32]
__device__ __forceinline__ void pl32swap(u32& a, u32& b) {
#if __has_builtin(__builtin_amdgcn_permlane32_swap)
    u32x2 r = __builtin_amdgcn_permlane32_swap(a, b, false, false);
    a = r[0]; b = r[1];
#else
    asm volatile("v_permlane32_swap_b32 %0, %1" : "+v"(a), "+v"(b));
#endif
}
// pl16: a' = [a.q0, b.q0, a.q2, b.q2], b' = [a.q1, b.q1, a.q3, b.q3]  (q = 16-lane row)
__device__ __forceinline__ void pl16swap(u32& a, u32& b) {
#if __has_builtin(__builtin_amdgcn_permlane16_swap)
    u32x2 r = __builtin_amdgcn_permlane16_swap(a, b, false, false);
    a = r[0]; b = r[1];
#else
    asm volatile("v_permlane16_swap_b32 %0, %1" : "+v"(a), "+v"(b));
#endif
}

// q-scale: 1/sqrt(64) * log2(e), so attention scores land in log2 domain
#define QSCALE 0.18033688011112042f

// ============ merge to fp16: rows 0..3071 = q,k,v; 3072..4095 = o ============
// vectorized x4: one block = one 1024-col row, float4 loads, ushort4 store
__global__ __launch_bounds__(256) void merge_w16(
    const float* __restrict__ w0, const float* __restrict__ dw0, const float* __restrict__ db0,
    const float* __restrict__ w1, const float* __restrict__ dw1, const float* __restrict__ db1,
    const float* __restrict__ w2, const float* __restrict__ dw2, const float* __restrict__ db2,
    const float* __restrict__ w3, const float* __restrict__ dw3, const float* __restrict__ db3,
    u16* __restrict__ Wf) {
    int i4 = (blockIdx.x * 256 + threadIdx.x) * 4;   // over 4096*1024
    int row = i4 >> 10, col = i4 & 1023;
    int which = row >> 10, lr = row & 1023;
    const float* W  = (which == 0) ? w0  : (which == 1) ? w1  : (which == 2) ? w2  : w3;
    const float* dW = (which == 0) ? dw0 : (which == 1) ? dw1 : (which == 2) ? dw2 : dw3;
    const float* dB = (which == 0) ? db0 : (which == 1) ? db1 : (which == 2) ? db2 : db3;
    float4 acc = *(const float4*)&W[lr * 1024 + col];
#pragma unroll
    for (int r = 0; r < 5; ++r) {
        float s = dB[lr * 5 + r];                    // block-uniform
        float4 w4 = *(const float4*)&dW[r * 1024 + col];
        acc.x += s * w4.x; acc.y += s * w4.y;
        acc.z += s * w4.z; acc.w += s * w4.w;
    }
    if (which == 0) { acc.x *= QSCALE; acc.y *= QSCALE; acc.z *= QSCALE; acc.w *= QSCALE; }
    ushort4 o = make_ushort4(f2h(acc.x), f2h(acc.y), f2h(acc.z), f2h(acc.w));
    *(ushort4*)&Wf[i4] = o;
}

__global__ __launch_bounds__(256) void bias_pack(
    const float* __restrict__ b0, const float* __restrict__ b1,
    const float* __restrict__ b2, const float* __restrict__ b3,
    float* __restrict__ ball) {
    int t = blockIdx.x * 256 + threadIdx.x;   // 4096
    int which = t >> 10;
    const float* B = (which == 0) ? b0 : (which == 1) ? b1 : (which == 2) ? b2 : b3;
    float v = B[t & 1023];
    if (which == 0) v *= QSCALE;
    ball[t] = v;
}

// x -> single fp16 (RNE)
__global__ __launch_bounds__(256) void xcast(const float* __restrict__ x,
                                             u16* __restrict__ xf) {
    int i4 = (blockIdx.x * 256 + threadIdx.x) * 4;
    float4 v = *(const float4*)&x[i4];
    *(uint2*)&xf[i4] = make_uint2(pk_h2(v.x, v.y), pk_h2(v.z, v.w));
}

// ============ fp16 GEMM: C[4096][N] = A @ B^T + bias ============
// Single fp16 product. TM x 128 tile, BK=64 staged as two 32-col halves
// (each half keeps the packed [row][32] m97 bank layout), global_load_lds(16).
// If VtOut: column blocks bn >= 2048 (V third of fused QKV) store TRANSPOSED
// to VtOut[(col-2048)][4096].
template <int TM>
__global__ __launch_bounds__(256) void gemm_f16(
    const u16* __restrict__ Af, const u16* __restrict__ Bf,
    const float* __restrict__ bias,
    float* __restrict__ Cf, u16* __restrict__ Cb, int ldc,
    u16* __restrict__ VtOut) {
    constexpr int MI = TM / 32;               // m-subtiles per wave
    __shared__ u16 As[2][TM * 32];
    __shared__ u16 Bs[2][128 * 32];
    const int tid = threadIdx.x;
    const int wid = tid >> 6, lane = tid & 63;
    const int ln = lane & 15, quad = lane >> 4;
    const int bm = blockIdx.y * TM, bn = blockIdx.x * 128;
    const int wm = (wid >> 1) * (TM / 2), wn = (wid & 1) * 64;
    const int lrow = lane >> 2;               // DMA: row within 16-row group
    const int lchunk = (lane & 3) * 8;        // DMA: u16 offset of 16B chunk

    f32x4 acc[MI][4];
#pragma unroll
    for (int i = 0; i < MI; ++i)
#pragma unroll
        for (int j = 0; j < 4; ++j) acc[i][j] = (f32x4){0.f, 0.f, 0.f, 0.f};

    for (int k0 = 0; k0 < 1024; k0 += 64) {
#pragma unroll
        for (int hf = 0; hf < 2; ++hf) {
#pragma unroll
            for (int p = 0; p < TM / 64; ++p) {
                int r = p * 64 + wid * 16;
                glds16(&Af[(bm + r + lrow) * 1024 + k0 + hf * 32 + lchunk],
                       &As[hf][r * 32]);
            }
#pragma unroll
            for (int p = 0; p < 2; ++p) {
                int r = p * 64 + wid * 16;
                glds16(&Bf[(bn + r + lrow) * 1024 + k0 + hf * 32 + lchunk],
                       &Bs[hf][r * 32]);
            }
        }
        asm volatile("s_waitcnt vmcnt(0)" ::: "memory");
        __syncthreads();

        half8 a[MI][2], b[4][2];
#pragma unroll
        for (int kc = 0; kc < 2; ++kc) {
#pragma unroll
            for (int j = 0; j < 4; ++j)
                b[j][kc] = *(const half8*)&Bs[kc][(wn + j * 16 + ln) * 32 + quad * 8];
#pragma unroll
            for (int i = 0; i < MI; ++i)
                a[i][kc] = *(const half8*)&As[kc][(wm + i * 16 + ln) * 32 + quad * 8];
        }
#pragma unroll
        for (int i = 0; i < MI; ++i)
#pragma unroll
            for (int j = 0; j < 4; ++j) {
                acc[i][j] = MFMAH(a[i][0], b[j][0], acc[i][j]);
                acc[i][j] = MFMAH(a[i][1], b[j][1], acc[i][j]);
            }
        __syncthreads();
    }

    if (VtOut && bn >= 2048) {
        // transposed store: VtOut[d][seq]; lane holds 4 consecutive seq rows.
#pragma unroll
        for (int i = 0; i < MI; ++i)
#pragma unroll
            for (int j = 0; j < 4; ++j) {
                int col = bn + wn + j * 16 + ln;
                float bv = bias[col];
                int colV = col - 2048;
                int row0 = bm + wm + i * 16 + quad * 4;
                ushort4 pk = make_ushort4(f2h(acc[i][j][0] + bv), f2h(acc[i][j][1] + bv),
                                          f2h(acc[i][j][2] + bv), f2h(acc[i][j][3] + bv));
                *(ushort4*)&VtOut[colV * 4096 + row0] = pk;
            }
        return;
    }

#pragma unroll
    for (int i = 0; i < MI; ++i)
#pragma unroll
        for (int j = 0; j < 4; ++j) {
            int col = bn + wn + j * 16 + ln;
            float bv = bias[col];
#pragma unroll
            for (int r = 0; r < 4; ++r) {
                int row = bm + wm + i * 16 + quad * 4 + r;
                float v = acc[i][j][r] + bv;
                if (Cb) Cb[row * ldc + col] = f2h(v);
                else    Cf[row * ldc + col] = v;
            }
        }
}

// ============ flash attention, fp16 MFMA, transposed S/O ============
// Block: 4 waves x 32 q-rows = 128 q of one (b,h). 64-key tiles.
// K staged via glds16 into packed [key][32]-per-half layout with XOR chunk
// swizzle (phys 16B chunk = logical ^ ((row>>1)&3)), applied BOTH sides ->
// 0 bank conflicts (verified R2). V fragments are REGISTER double-buffered:
// direct global loads (contiguous 16B/lane from Vt) issued ONE TILE AHEAD
// alongside the K DMA, so their L1/L2 latency hides behind a full tile of
// compute; the per-tile vmcnt(0)+barrier guarantees they have landed.
// Loop processes 2 tiles/iteration with named vfA/vfB so all register
// arrays are statically indexed (no scratch). Scores in log2 domain ->
// p = v_exp_f32 raw. S->P transform in-register: cvt_pkrtz + permlane32/16
// butterfly. Row sums via ones-MFMA.
__global__ __launch_bounds__(256) void flash_f16(
    const u16* __restrict__ QKV, const u16* __restrict__ Vt,
    u16* __restrict__ AO) {
    __shared__ u16 Ks[2][2][64 * 32];   // [buf][d-half][key row][32], chunk-swizzled

    const int tid = threadIdx.x;
    const int wid = tid >> 6, lane = tid & 63;
    const int ln = lane & 15, quad = lane >> 4;
    const int qt = blockIdx.x, h = blockIdx.y, b = blockIdx.z;
    const int rowbase = b * NQ;
    const int col0 = h * 64;
    const int q0 = rowbase + qt * 128 + wid * 32;
    const int lrow = lane >> 2;          // DMA: row within 16-row group
    // DMA source chunk (pre-swizzle): lane l fetches logical chunk (l&3)^((lrow>>1)&3)
    const int kchunk = ((lane & 3) ^ ((lrow >> 1) & 3)) * 8;
    // fragment-read physical chunk: quad ^ ((row>>1)&3), row&15 == ln
    const int kswz = (quad ^ ((ln >> 1) & 3)) * 8;

    const half8 ones = {(f16)1, (f16)1, (f16)1, (f16)1,
                        (f16)1, (f16)1, (f16)1, (f16)1};

    // Q fragments (B-operand: lane ln = q-row q0+mi*16+ln, k = kc*32+quad*8+j)
    half8 qf[2][2];
#pragma unroll
    for (int mi = 0; mi < 2; ++mi)
#pragma unroll
        for (int kc = 0; kc < 2; ++kc)
            qf[mi][kc] = *(const half8*)&QKV[(q0 + mi * 16 + ln) * 3072 + col0 +
                                             kc * 32 + quad * 8];

    f32x4 accO[4][2];    // [a: d-subtile][mi], element (d=a*16+quad*4+r, q=mi*16+ln)
    f32x4 accS[2];       // row sums, col = q = ln
#pragma unroll
    for (int mi = 0; mi < 2; ++mi) {
        accS[mi] = (f32x4){0.f, 0.f, 0.f, 0.f};
#pragma unroll
        for (int a = 0; a < 4; ++a) accO[a][mi] = (f32x4){0.f, 0.f, 0.f, 0.f};
    }

    const int NT = NQ / 64;
    // K DMA per-lane global base (16 rows x 64B per glds16 call per wave)
    const u16* Kg = QKV + (rowbase + wid * 16 + lrow) * 3072 + 1024 + col0 + kchunk;
    // V fragment direct-load base: element (d = col0+a*16+ln, seq = kt*64+hf*32+quad*8+j)
    const u16* Vg = Vt + (col0 + ln) * 4096 + rowbase + quad * 8;

#define STAGEK(kt2, bu)                                        \
    {                                                          \
        const u16* kg_ = Kg + (kt2) * (64 * 3072);             \
        glds16(kg_,      &Ks[bu][0][wid * 512]);               \
        glds16(kg_ + 32, &Ks[bu][1][wid * 512]);               \
    }

    half8 vfA[4][2], vfB[4][2];   // V register double buffer (statically indexed)

    auto loadV = [&](half8 (&dst)[4][2], int kt2) {
#pragma unroll
        for (int a = 0; a < 4; ++a)
#pragma unroll
            for (int hf = 0; hf < 2; ++hf)
                dst[a][hf] = *(const half8*)&Vg[a * 16 * 4096 + kt2 * 64 + hf * 32];
    };

    // one 64-key tile: QK^T from Ks[kb], exp+butterfly, row-sum, PV from vfx
    auto tile = [&](const half8 (&vfx)[4][2], int kb) {
        // S^T = K @ Q^T : element (key = a*16+quad*4+r, q = mi*16+ln)
        f32x4 s[4][2];
#pragma unroll
        for (int a = 0; a < 4; ++a) {
            half8 kf0 = *(const half8*)&Ks[kb][0][(a * 16 + ln) * 32 + kswz];
            half8 kf1 = *(const half8*)&Ks[kb][1][(a * 16 + ln) * 32 + kswz];
#pragma unroll
            for (int mi = 0; mi < 2; ++mi) {
                f32x4 t = (f32x4){0.f, 0.f, 0.f, 0.f};
                t = MFMAH(kf0, qf[mi][0], t);
                t = MFMAH(kf1, qf[mi][1], t);
                s[a][mi] = t;
            }
        }

        // p = 2^s, pack to fp16 pairs, then register butterfly to B-operand
        // layout: pf[mi][kc] element j = P[key = kc*32 + quad*8 + j][q = mi*16+ln].
        half8 pf[2][2];
#pragma unroll
        for (int mi = 0; mi < 2; ++mi)
#pragma unroll
            for (int kc = 0; kc < 2; ++kc) {
                u32 c0 = pk_h2(fexp2(s[2 * kc][mi][0]), fexp2(s[2 * kc][mi][1]));
                u32 c1 = pk_h2(fexp2(s[2 * kc][mi][2]), fexp2(s[2 * kc][mi][3]));
                u32 c2 = pk_h2(fexp2(s[2 * kc + 1][mi][0]), fexp2(s[2 * kc + 1][mi][1]));
                u32 c3 = pk_h2(fexp2(s[2 * kc + 1][mi][2]), fexp2(s[2 * kc + 1][mi][3]));
                pl32swap(c0, c2);
                pl32swap(c1, c3);
                pl16swap(c0, c2);
                pl16swap(c1, c3);
                union { u32 u[4]; half8 h; } pu;
                pu.u[0] = c0; pu.u[1] = c1; pu.u[2] = c2; pu.u[3] = c3;
                pf[mi][kc] = pu.h;
                accS[mi] = MFMAH(ones, pf[mi][kc], accS[mi]);   // row sums
            }

        // O^T += V^T @ P^T : element (d = a*16+quad*4+r, q = mi*16+ln)
#pragma unroll
        for (int a = 0; a < 4; ++a)
#pragma unroll
            for (int mi = 0; mi < 2; ++mi) {
                accO[a][mi] = MFMAH(vfx[a][0], pf[mi][0], accO[a][mi]);
                accO[a][mi] = MFMAH(vfx[a][1], pf[mi][1], accO[a][mi]);
            }
    };

    // prologue: stage tile 0 (K -> LDS, V -> regs)
    STAGEK(0, 0);
    loadV(vfA, 0);
    asm volatile("s_waitcnt vmcnt(0)" ::: "memory");
    __syncthreads();

    for (int kt = 0; kt < NT; kt += 2) {
        // prefetch tile kt+1 (always exists: NT even), compute tile kt
        STAGEK(kt + 1, 1);
        loadV(vfB, kt + 1);
        tile(vfA, 0);
        asm volatile("s_waitcnt vmcnt(0)" ::: "memory");   // kt+1 staged
        __syncthreads();                                   // all waves done with Ks[0]

        // prefetch tile kt+2, compute tile kt+1
        if (kt + 2 < NT) {
            STAGEK(kt + 2, 0);
            loadV(vfA, kt + 2);
        }
        tile(vfB, 1);
        asm volatile("s_waitcnt vmcnt(0)" ::: "memory");
        __syncthreads();
    }
#undef STAGEK

    // epilogue: normalize (inv uniform per lane), single fp16 AO, ushort4 stores
#pragma unroll
    for (int mi = 0; mi < 2; ++mi) {
        float inv = 1.f / accS[mi][0];
        int q = q0 + mi * 16 + ln;
#pragma unroll
        for (int a = 0; a < 4; ++a) {
            ushort4 pk = make_ushort4(f2h(accO[a][mi][0] * inv),
                                      f2h(accO[a][mi][1] * inv),
                                      f2h(accO[a][mi][2] * inv),
                                      f2h(accO[a][mi][3] * inv));
            *(ushort4*)&AO[q * 1024 + col0 + a * 16 + quad * 4] = pk;
        }
    }
}

// ============ launch ============
extern "C" void kernel_launch(void* const* d_in, const int* in_sizes, int n_in,
                              void* d_out, int out_size, void* d_ws, size_t ws_size,
                              hipStream_t stream) {
    const float* x = (const float*)d_in[0];
    const float* w[4]  = {(const float*)d_in[1],  (const float*)d_in[5],
                          (const float*)d_in[9],  (const float*)d_in[13]};
    const float* bv[4] = {(const float*)d_in[2],  (const float*)d_in[6],
                          (const float*)d_in[10], (const float*)d_in[14]};
    const float* dw[4] = {(const float*)d_in[3],  (const float*)d_in[7],
                          (const float*)d_in[11], (const float*)d_in[15]};
    const float* db[4] = {(const float*)d_in[4],  (const float*)d_in[8],
                          (const float*)d_in[12], (const float*)d_in[16]};

    u16* p = (u16*)d_ws;
    u16* Wf  = p; p += 4096 * 1024;
    u16* xf  = p; p += 4096 * 1024;
    u16* QKV = p; p += 4096 * 3072;   // V third unused (lives in Vt)
    u16* Vt  = p; p += 1024 * 4096;
    float* ball = (float*)p;          // 4096 floats
    // AO aliases xf: x is dead after the QKV GEMM completes (same stream).
    u16* AO = xf;

    merge_w16<<<4096, 256, 0, stream>>>(w[0], dw[0], db[0], w[1], dw[1], db[1],
                                        w[2], dw[2], db[2], w[3], dw[3], db[3], Wf);
    bias_pack<<<16, 256, 0, stream>>>(bv[0], bv[1], bv[2], bv[3], ball);
    xcast<<<4096, 256, 0, stream>>>(x, xf);

    // fused q,k,v projection: q,k -> QKV fp16 row-major; v -> Vt transposed
    gemm_f16<128><<<dim3(24, 32), 256, 0, stream>>>(xf, Wf, ball,
                                                    nullptr, QKV, 3072, Vt);

    flash_f16<<<dim3(NQ / 128, 16, NB), 256, 0, stream>>>(QKV, Vt, AO);

    // o projection: fp32 out, TM=64 -> 512 blocks (2 blocks/CU)
    gemm_f16<64><<<dim3(8, 64), 256, 0, stream>>>(AO, Wf + 3072 * 1024,
                                                  ball + 3072, (float*)d_out, nullptr, 1024,
                                                  nullptr);
}

// Round 4
// 227.841 us; speedup vs baseline: 1.1155x; 1.1143x over previous
//
#include <hip/hip_runtime.h>
#include <hip/hip_bf16.h>

#define NQ 2048
#define NB 2

typedef unsigned short u16;
typedef unsigned int u32;
typedef _Float16 f16;
typedef __attribute__((ext_vector_type(8))) _Float16 half8;
typedef __attribute__((ext_vector_type(2))) __fp16 fp16x2;
typedef __attribute__((ext_vector_type(4))) float f32x4;
typedef __attribute__((ext_vector_type(2))) unsigned int u32x2;

#define MFMAH(A, B, C) __builtin_amdgcn_mfma_f32_16x16x32_f16(A, B, C, 0, 0, 0)

__device__ __forceinline__ u16 f2h(float x) {
    f16 h = (f16)x;                 // v_cvt_f16_f32 (RNE)
    return *(u16*)&h;
}
// packed f32x2 -> fp16x2 (v_cvt_pkrtz_f16_f32), returned as u32
__device__ __forceinline__ u32 pk_h2(float a, float b) {
    union { fp16x2 v; u32 u; } c;
    c.v = __builtin_amdgcn_cvt_pkrtz(a, b);
    return c.u;
}
// raw v_exp_f32 (2^x)
__device__ __forceinline__ float fexp2(float x) {
#if __has_builtin(__builtin_amdgcn_exp2f)
    return __builtin_amdgcn_exp2f(x);
#else
    return exp2f(x);
#endif
}
// async global->LDS DMA, 16B/lane; lds dest is wave-uniform base + lane*16
__device__ __forceinline__ void glds16(const u16* g, u16* l) {
    typedef const __attribute__((address_space(1))) u16 gu16;
    typedef __attribute__((address_space(3))) u16 lu16;
    __builtin_amdgcn_global_load_lds((gu16*)g, (lu16*)l, 16, 0, 0);
}
// VALU cross-lane swaps (gfx950): a/b both updated.
// pl32: a' = [a.lo32, b.lo32], b' = [a.hi32, b.hi32]
__device__ __forceinline__ void pl32swap(u32& a, u32& b) {
#if __has_builtin(__builtin_amdgcn_permlane32_swap)
    u32x2 r = __builtin_amdgcn_permlane32_swap(a, b, false, false);
    a = r[0]; b = r[1];
#else
    asm volatile("v_permlane32_swap_b32 %0, %1" : "+v"(a), "+v"(b));
#endif
}
// pl16: a' = [a.q0, b.q0, a.q2, b.q2], b' = [a.q1, b.q1, a.q3, b.q3]  (q = 16-lane row)
__device__ __forceinline__ void pl16swap(u32& a, u32& b) {
#if __has_builtin(__builtin_amdgcn_permlane16_swap)
    u32x2 r = __builtin_amdgcn_permlane16_swap(a, b, false, false);
    a = r[0]; b = r[1];
#else
    asm volatile("v_permlane16_swap_b32 %0, %1" : "+v"(a), "+v"(b));
#endif
}

// q-scale: 1/sqrt(64) * log2(e), so attention scores land in log2 domain
#define QSCALE 0.18033688011112042f

// ============ merge to fp16: rows 0..3071 = q,k,v; 3072..4095 = o ============
// vectorized x4: one block = one 1024-col row, float4 loads, ushort4 store
__global__ __launch_bounds__(256) void merge_w16(
    const float* __restrict__ w0, const float* __restrict__ dw0, const float* __restrict__ db0,
    const float* __restrict__ w1, const float* __restrict__ dw1, const float* __restrict__ db1,
    const float* __restrict__ w2, const float* __restrict__ dw2, const float* __restrict__ db2,
    const float* __restrict__ w3, const float* __restrict__ dw3, const float* __restrict__ db3,
    u16* __restrict__ Wf) {
    int i4 = (blockIdx.x * 256 + threadIdx.x) * 4;   // over 4096*1024
    int row = i4 >> 10, col = i4 & 1023;
    int which = row >> 10, lr = row & 1023;
    const float* W  = (which == 0) ? w0  : (which == 1) ? w1  : (which == 2) ? w2  : w3;
    const float* dW = (which == 0) ? dw0 : (which == 1) ? dw1 : (which == 2) ? dw2 : dw3;
    const float* dB = (which == 0) ? db0 : (which == 1) ? db1 : (which == 2) ? db2 : db3;
    float4 acc = *(const float4*)&W[lr * 1024 + col];
#pragma unroll
    for (int r = 0; r < 5; ++r) {
        float s = dB[lr * 5 + r];                    // block-uniform
        float4 w4 = *(const float4*)&dW[r * 1024 + col];
        acc.x += s * w4.x; acc.y += s * w4.y;
        acc.z += s * w4.z; acc.w += s * w4.w;
    }
    if (which == 0) { acc.x *= QSCALE; acc.y *= QSCALE; acc.z *= QSCALE; acc.w *= QSCALE; }
    ushort4 o = make_ushort4(f2h(acc.x), f2h(acc.y), f2h(acc.z), f2h(acc.w));
    *(ushort4*)&Wf[i4] = o;
}

__global__ __launch_bounds__(256) void bias_pack(
    const float* __restrict__ b0, const float* __restrict__ b1,
    const float* __restrict__ b2, const float* __restrict__ b3,
    float* __restrict__ ball) {
    int t = blockIdx.x * 256 + threadIdx.x;   // 4096
    int which = t >> 10;
    const float* B = (which == 0) ? b0 : (which == 1) ? b1 : (which == 2) ? b2 : b3;
    float v = B[t & 1023];
    if (which == 0) v *= QSCALE;
    ball[t] = v;
}

// x -> single fp16 (RNE)
__global__ __launch_bounds__(256) void xcast(const float* __restrict__ x,
                                             u16* __restrict__ xf) {
    int i4 = (blockIdx.x * 256 + threadIdx.x) * 4;
    float4 v = *(const float4*)&x[i4];
    *(uint2*)&xf[i4] = make_uint2(pk_h2(v.x, v.y), pk_h2(v.z, v.w));
}

// ============ fp16 GEMM: C[4096][N] = A @ B^T + bias ============
// Single fp16 product. TM x 128 tile, BK=64 staged as two 32-col halves
// (each half keeps the packed [row][32] m97 bank layout), global_load_lds(16).
// If VtOut: column blocks bn >= 2048 (V third of fused QKV) store TRANSPOSED
// to VtOut[(col-2048)][4096].
template <int TM>
__global__ __launch_bounds__(256) void gemm_f16(
    const u16* __restrict__ Af, const u16* __restrict__ Bf,
    const float* __restrict__ bias,
    float* __restrict__ Cf, u16* __restrict__ Cb, int ldc,
    u16* __restrict__ VtOut) {
    constexpr int MI = TM / 32;               // m-subtiles per wave
    __shared__ u16 As[2][TM * 32];
    __shared__ u16 Bs[2][128 * 32];
    const int tid = threadIdx.x;
    const int wid = tid >> 6, lane = tid & 63;
    const int ln = lane & 15, quad = lane >> 4;
    const int bm = blockIdx.y * TM, bn = blockIdx.x * 128;
    const int wm = (wid >> 1) * (TM / 2), wn = (wid & 1) * 64;
    const int lrow = lane >> 2;               // DMA: row within 16-row group
    const int lchunk = (lane & 3) * 8;        // DMA: u16 offset of 16B chunk

    f32x4 acc[MI][4];
#pragma unroll
    for (int i = 0; i < MI; ++i)
#pragma unroll
        for (int j = 0; j < 4; ++j) acc[i][j] = (f32x4){0.f, 0.f, 0.f, 0.f};

    for (int k0 = 0; k0 < 1024; k0 += 64) {
#pragma unroll
        for (int hf = 0; hf < 2; ++hf) {
#pragma unroll
            for (int p = 0; p < TM / 64; ++p) {
                int r = p * 64 + wid * 16;
                glds16(&Af[(bm + r + lrow) * 1024 + k0 + hf * 32 + lchunk],
                       &As[hf][r * 32]);
            }
#pragma unroll
            for (int p = 0; p < 2; ++p) {
                int r = p * 64 + wid * 16;
                glds16(&Bf[(bn + r + lrow) * 1024 + k0 + hf * 32 + lchunk],
                       &Bs[hf][r * 32]);
            }
        }
        asm volatile("s_waitcnt vmcnt(0)" ::: "memory");
        __syncthreads();

        half8 a[MI][2], b[4][2];
#pragma unroll
        for (int kc = 0; kc < 2; ++kc) {
#pragma unroll
            for (int j = 0; j < 4; ++j)
                b[j][kc] = *(const half8*)&Bs[kc][(wn + j * 16 + ln) * 32 + quad * 8];
#pragma unroll
            for (int i = 0; i < MI; ++i)
                a[i][kc] = *(const half8*)&As[kc][(wm + i * 16 + ln) * 32 + quad * 8];
        }
#pragma unroll
        for (int i = 0; i < MI; ++i)
#pragma unroll
            for (int j = 0; j < 4; ++j) {
                acc[i][j] = MFMAH(a[i][0], b[j][0], acc[i][j]);
                acc[i][j] = MFMAH(a[i][1], b[j][1], acc[i][j]);
            }
        __syncthreads();
    }

    if (VtOut && bn >= 2048) {
        // transposed store: VtOut[d][seq]; lane holds 4 consecutive seq rows.
#pragma unroll
        for (int i = 0; i < MI; ++i)
#pragma unroll
            for (int j = 0; j < 4; ++j) {
                int col = bn + wn + j * 16 + ln;
                float bv = bias[col];
                int colV = col - 2048;
                int row0 = bm + wm + i * 16 + quad * 4;
                ushort4 pk = make_ushort4(f2h(acc[i][j][0] + bv), f2h(acc[i][j][1] + bv),
                                          f2h(acc[i][j][2] + bv), f2h(acc[i][j][3] + bv));
                *(ushort4*)&VtOut[colV * 4096 + row0] = pk;
            }
        return;
    }

#pragma unroll
    for (int i = 0; i < MI; ++i)
#pragma unroll
        for (int j = 0; j < 4; ++j) {
            int col = bn + wn + j * 16 + ln;
            float bv = bias[col];
#pragma unroll
            for (int r = 0; r < 4; ++r) {
                int row = bm + wm + i * 16 + quad * 4 + r;
                float v = acc[i][j][r] + bv;
                if (Cb) Cb[row * ldc + col] = f2h(v);
                else    Cf[row * ldc + col] = v;
            }
        }
}

// ============ flash attention, fp16 MFMA, transposed S/O ============
// Block: 4 waves x 32 q-rows = 128 q of one (b,h). 64-key tiles.
// K AND V both staged via glds16 (1x traffic, shared by all 4 waves) into
// packed [row][32]-per-half layout with XOR chunk swizzle (phys 16B chunk =
// logical ^ ((row>>1)&3)), applied BOTH sides: pre-swizzled global source on
// the DMA, swizzled address on ds_read -> 0 bank conflicts (verified R2 on K;
// V fragment pattern is identical). Double-buffered, one vmcnt(0)+barrier per
// tile. Scores in log2 domain -> p = v_exp_f32 raw. S->P transform fully
// in-register: cvt_pkrtz + permlane32/16 butterfly. Row sums via ones-MFMA.
// (R2/R3 lesson: direct-global V fragments cost 4x redundant scattered VMEM
// traffic -> +28us, latency-prefetch does NOT recover it. LDS staging does.)
__global__ __launch_bounds__(256) void flash_f16(
    const u16* __restrict__ QKV, const u16* __restrict__ Vt,
    u16* __restrict__ AO) {
    __shared__ u16 Ks[2][2][64 * 32];   // [buf][d-half][key row][32], chunk-swizzled
    __shared__ u16 Vs[2][2][64 * 32];   // [buf][key-half][d row][32], chunk-swizzled

    const int tid = threadIdx.x;
    const int wid = tid >> 6, lane = tid & 63;
    const int ln = lane & 15, quad = lane >> 4;
    const int qt = blockIdx.x, h = blockIdx.y, b = blockIdx.z;
    const int rowbase = b * NQ;
    const int col0 = h * 64;
    const int q0 = rowbase + qt * 128 + wid * 32;
    const int lrow = lane >> 2;          // DMA: row within 16-row group
    // DMA source chunk (pre-swizzle): lane l fetches logical chunk (l&3)^((lrow>>1)&3)
    const int kchunk = ((lane & 3) ^ ((lrow >> 1) & 3)) * 8;
    // fragment-read physical chunk: quad ^ ((row>>1)&3), (row>>1)&3 == (ln>>1)&3
    const int kswz = (quad ^ ((ln >> 1) & 3)) * 8;

    const half8 ones = {(f16)1, (f16)1, (f16)1, (f16)1,
                        (f16)1, (f16)1, (f16)1, (f16)1};

    // Q fragments (B-operand: lane ln = q-row q0+mi*16+ln, k = kc*32+quad*8+j)
    half8 qf[2][2];
#pragma unroll
    for (int mi = 0; mi < 2; ++mi)
#pragma unroll
        for (int kc = 0; kc < 2; ++kc)
            qf[mi][kc] = *(const half8*)&QKV[(q0 + mi * 16 + ln) * 3072 + col0 +
                                             kc * 32 + quad * 8];

    f32x4 accO[4][2];    // [a: d-subtile][mi], element (d=a*16+quad*4+r, q=mi*16+ln)
    f32x4 accS[2];       // row sums, col = q = ln
#pragma unroll
    for (int mi = 0; mi < 2; ++mi) {
        accS[mi] = (f32x4){0.f, 0.f, 0.f, 0.f};
#pragma unroll
        for (int a = 0; a < 4; ++a) accO[a][mi] = (f32x4){0.f, 0.f, 0.f, 0.f};
    }

    const int NT = NQ / 64;
    // DMA per-lane global bases (16 rows x 64B per glds16 call per wave)
    const u16* Kg = QKV + (rowbase + wid * 16 + lrow) * 3072 + 1024 + col0 + kchunk;
    const u16* Vg = Vt + (col0 + wid * 16 + lrow) * 4096 + rowbase + kchunk;

#define STAGE(kt2, bu)                                         \
    {                                                          \
        const u16* kg_ = Kg + (kt2) * (64 * 3072);             \
        const u16* vg_ = Vg + (kt2) * 64;                      \
        glds16(kg_,      &Ks[bu][0][wid * 512]);               \
        glds16(kg_ + 32, &Ks[bu][1][wid * 512]);               \
        glds16(vg_,      &Vs[bu][0][wid * 512]);               \
        glds16(vg_ + 32, &Vs[bu][1][wid * 512]);               \
    }

    // prologue: stage tile 0
    STAGE(0, 0);
    asm volatile("s_waitcnt vmcnt(0)" ::: "memory");
    __syncthreads();

#pragma unroll 2
    for (int kt = 0; kt < NT; ++kt) {
        const int cur = kt & 1;
        if (kt + 1 < NT) STAGE(kt + 1, cur ^ 1);   // DMA overlaps this tile's compute

        // S^T = K @ Q^T : element (key = a*16+quad*4+r, q = mi*16+ln)
        f32x4 s[4][2];
#pragma unroll
        for (int a = 0; a < 4; ++a) {
            half8 kf0 = *(const half8*)&Ks[cur][0][(a * 16 + ln) * 32 + kswz];
            half8 kf1 = *(const half8*)&Ks[cur][1][(a * 16 + ln) * 32 + kswz];
#pragma unroll
            for (int mi = 0; mi < 2; ++mi) {
                f32x4 t = (f32x4){0.f, 0.f, 0.f, 0.f};
                t = MFMAH(kf0, qf[mi][0], t);
                t = MFMAH(kf1, qf[mi][1], t);
                s[a][mi] = t;
            }
        }

        // p = 2^s, pack to fp16 pairs, then register butterfly to B-operand
        // layout: pf[mi][kc] element j = P[key = kc*32 + quad*8 + j][q = mi*16+ln].
        half8 pf[2][2];
#pragma unroll
        for (int mi = 0; mi < 2; ++mi)
#pragma unroll
            for (int kc = 0; kc < 2; ++kc) {
                u32 c0 = pk_h2(fexp2(s[2 * kc][mi][0]), fexp2(s[2 * kc][mi][1]));
                u32 c1 = pk_h2(fexp2(s[2 * kc][mi][2]), fexp2(s[2 * kc][mi][3]));
                u32 c2 = pk_h2(fexp2(s[2 * kc + 1][mi][0]), fexp2(s[2 * kc + 1][mi][1]));
                u32 c3 = pk_h2(fexp2(s[2 * kc + 1][mi][2]), fexp2(s[2 * kc + 1][mi][3]));
                pl32swap(c0, c2);
                pl32swap(c1, c3);
                pl16swap(c0, c2);
                pl16swap(c1, c3);
                union { u32 u[4]; half8 h; } pu;
                pu.u[0] = c0; pu.u[1] = c1; pu.u[2] = c2; pu.u[3] = c3;
                pf[mi][kc] = pu.h;
                accS[mi] = MFMAH(ones, pf[mi][kc], accS[mi]);   // row sums
            }

        // O^T += V^T @ P^T : element (d = a*16+quad*4+r, q = mi*16+ln)
#pragma unroll
        for (int a = 0; a < 4; ++a) {
            half8 vf0 = *(const half8*)&Vs[cur][0][(a * 16 + ln) * 32 + kswz];
            half8 vf1 = *(const half8*)&Vs[cur][1][(a * 16 + ln) * 32 + kswz];
#pragma unroll
            for (int mi = 0; mi < 2; ++mi) {
                accO[a][mi] = MFMAH(vf0, pf[mi][0], accO[a][mi]);
                accO[a][mi] = MFMAH(vf1, pf[mi][1], accO[a][mi]);
            }
        }

        asm volatile("s_waitcnt vmcnt(0)" ::: "memory");   // next tile landed
        __syncthreads();                                   // all waves done with cur
    }
#undef STAGE

    // epilogue: normalize (inv uniform per lane), single fp16 AO, ushort4 stores
#pragma unroll
    for (int mi = 0; mi < 2; ++mi) {
        float inv = 1.f / accS[mi][0];
        int q = q0 + mi * 16 + ln;
#pragma unroll
        for (int a = 0; a < 4; ++a) {
            ushort4 pk = make_ushort4(f2h(accO[a][mi][0] * inv),
                                      f2h(accO[a][mi][1] * inv),
                                      f2h(accO[a][mi][2] * inv),
                                      f2h(accO[a][mi][3] * inv));
            *(ushort4*)&AO[q * 1024 + col0 + a * 16 + quad * 4] = pk;
        }
    }
}

// ============ launch ============
extern "C" void kernel_launch(void* const* d_in, const int* in_sizes, int n_in,
                              void* d_out, int out_size, void* d_ws, size_t ws_size,
                              hipStream_t stream) {
    const float* x = (const float*)d_in[0];
    const float* w[4]  = {(const float*)d_in[1],  (const float*)d_in[5],
                          (const float*)d_in[9],  (const float*)d_in[13]};
    const float* bv[4] = {(const float*)d_in[2],  (const float*)d_in[6],
                          (const float*)d_in[10], (const float*)d_in[14]};
    const float* dw[4] = {(const float*)d_in[3],  (const float*)d_in[7],
                          (const float*)d_in[11], (const float*)d_in[15]};
    const float* db[4] = {(const float*)d_in[4],  (const float*)d_in[8],
                          (const float*)d_in[12], (const float*)d_in[16]};

    u16* p = (u16*)d_ws;
    u16* Wf  = p; p += 4096 * 1024;
    u16* xf  = p; p += 4096 * 1024;
    u16* QKV = p; p += 4096 * 3072;   // V third unused (lives in Vt)
    u16* Vt  = p; p += 1024 * 4096;
    float* ball = (float*)p;          // 4096 floats
    // AO aliases xf: x is dead after the QKV GEMM completes (same stream).
    u16* AO = xf;

    merge_w16<<<4096, 256, 0, stream>>>(w[0], dw[0], db[0], w[1], dw[1], db[1],
                                        w[2], dw[2], db[2], w[3], dw[3], db[3], Wf);
    bias_pack<<<16, 256, 0, stream>>>(bv[0], bv[1], bv[2], bv[3], ball);
    xcast<<<4096, 256, 0, stream>>>(x, xf);

    // fused q,k,v projection: q,k -> QKV fp16 row-major; v -> Vt transposed
    gemm_f16<128><<<dim3(24, 32), 256, 0, stream>>>(xf, Wf, ball,
                                                    nullptr, QKV, 3072, Vt);

    flash_f16<<<dim3(NQ / 128, 16, NB), 256, 0, stream>>>(QKV, Vt, AO);

    // o projection: fp32 out, TM=64 -> 512 blocks (2 blocks/CU)
    gemm_f16<64><<<dim3(8, 64), 256, 0, stream>>>(AO, Wf + 3072 * 1024,
                                                  ball + 3072, (float*)d_out, nullptr, 1024,
                                                  nullptr);
}

// Round 5
// 226.067 us; speedup vs baseline: 1.1242x; 1.0078x over previous
//
#include <hip/hip_runtime.h>
#include <hip/hip_bf16.h>

#define NQ 2048
#define NB 2

typedef unsigned short u16;
typedef unsigned int u32;
typedef _Float16 f16;
typedef __attribute__((ext_vector_type(8))) _Float16 half8;
typedef __attribute__((ext_vector_type(2))) __fp16 fp16x2;
typedef __attribute__((ext_vector_type(4))) float f32x4;
typedef __attribute__((ext_vector_type(2))) unsigned int u32x2;

#define MFMAH(A, B, C) __builtin_amdgcn_mfma_f32_16x16x32_f16(A, B, C, 0, 0, 0)

__device__ __forceinline__ u16 f2h(float x) {
    f16 h = (f16)x;                 // v_cvt_f16_f32 (RNE)
    return *(u16*)&h;
}
// packed f32x2 -> fp16x2 (v_cvt_pkrtz_f16_f32), returned as u32
__device__ __forceinline__ u32 pk_h2(float a, float b) {
    union { fp16x2 v; u32 u; } c;
    c.v = __builtin_amdgcn_cvt_pkrtz(a, b);
    return c.u;
}
// raw v_exp_f32 (2^x)
__device__ __forceinline__ float fexp2(float x) {
#if __has_builtin(__builtin_amdgcn_exp2f)
    return __builtin_amdgcn_exp2f(x);
#else
    return exp2f(x);
#endif
}
// async global->LDS DMA, 16B/lane; lds dest is wave-uniform base + lane*16
__device__ __forceinline__ void glds16(const u16* g, u16* l) {
    typedef const __attribute__((address_space(1))) u16 gu16;
    typedef __attribute__((address_space(3))) u16 lu16;
    __builtin_amdgcn_global_load_lds((gu16*)g, (lu16*)l, 16, 0, 0);
}
// VALU cross-lane swaps (gfx950): a/b both updated.
// pl32: a' = [a.lo32, b.lo32], b' = [a.hi32, b.hi32]
__device__ __forceinline__ void pl32swap(u32& a, u32& b) {
#if __has_builtin(__builtin_amdgcn_permlane32_swap)
    u32x2 r = __builtin_amdgcn_permlane32_swap(a, b, false, false);
    a = r[0]; b = r[1];
#else
    asm volatile("v_permlane32_swap_b32 %0, %1" : "+v"(a), "+v"(b));
#endif
}
// pl16: a' = [a.q0, b.q0, a.q2, b.q2], b' = [a.q1, b.q1, a.q3, b.q3]  (q = 16-lane row)
__device__ __forceinline__ void pl16swap(u32& a, u32& b) {
#if __has_builtin(__builtin_amdgcn_permlane16_swap)
    u32x2 r = __builtin_amdgcn_permlane16_swap(a, b, false, false);
    a = r[0]; b = r[1];
#else
    asm volatile("v_permlane16_swap_b32 %0, %1" : "+v"(a), "+v"(b));
#endif
}

// q-scale: 1/sqrt(64) * log2(e), so attention scores land in log2 domain
#define QSCALE 0.18033688011112042f

// ============ merge to fp16: rows 0..3071 = q,k,v; 3072..4095 = o ============
// vectorized x4: one block = one 1024-col row, float4 loads, ushort4 store
__global__ __launch_bounds__(256) void merge_w16(
    const float* __restrict__ w0, const float* __restrict__ dw0, const float* __restrict__ db0,
    const float* __restrict__ w1, const float* __restrict__ dw1, const float* __restrict__ db1,
    const float* __restrict__ w2, const float* __restrict__ dw2, const float* __restrict__ db2,
    const float* __restrict__ w3, const float* __restrict__ dw3, const float* __restrict__ db3,
    u16* __restrict__ Wf) {
    int i4 = (blockIdx.x * 256 + threadIdx.x) * 4;   // over 4096*1024
    int row = i4 >> 10, col = i4 & 1023;
    int which = row >> 10, lr = row & 1023;
    const float* W  = (which == 0) ? w0  : (which == 1) ? w1  : (which == 2) ? w2  : w3;
    const float* dW = (which == 0) ? dw0 : (which == 1) ? dw1 : (which == 2) ? dw2 : dw3;
    const float* dB = (which == 0) ? db0 : (which == 1) ? db1 : (which == 2) ? db2 : db3;
    float4 acc = *(const float4*)&W[lr * 1024 + col];
#pragma unroll
    for (int r = 0; r < 5; ++r) {
        float s = dB[lr * 5 + r];                    // block-uniform
        float4 w4 = *(const float4*)&dW[r * 1024 + col];
        acc.x += s * w4.x; acc.y += s * w4.y;
        acc.z += s * w4.z; acc.w += s * w4.w;
    }
    if (which == 0) { acc.x *= QSCALE; acc.y *= QSCALE; acc.z *= QSCALE; acc.w *= QSCALE; }
    ushort4 o = make_ushort4(f2h(acc.x), f2h(acc.y), f2h(acc.z), f2h(acc.w));
    *(ushort4*)&Wf[i4] = o;
}

__global__ __launch_bounds__(256) void bias_pack(
    const float* __restrict__ b0, const float* __restrict__ b1,
    const float* __restrict__ b2, const float* __restrict__ b3,
    float* __restrict__ ball) {
    int t = blockIdx.x * 256 + threadIdx.x;   // 4096
    int which = t >> 10;
    const float* B = (which == 0) ? b0 : (which == 1) ? b1 : (which == 2) ? b2 : b3;
    float v = B[t & 1023];
    if (which == 0) v *= QSCALE;
    ball[t] = v;
}

// x -> single fp16 (RNE)
__global__ __launch_bounds__(256) void xcast(const float* __restrict__ x,
                                             u16* __restrict__ xf) {
    int i4 = (blockIdx.x * 256 + threadIdx.x) * 4;
    float4 v = *(const float4*)&x[i4];
    *(uint2*)&xf[i4] = make_uint2(pk_h2(v.x, v.y), pk_h2(v.z, v.w));
}

// ============ fp16 GEMM: C[4096][N] = A @ B^T + bias ============
// Single fp16 product. TM x 128 tile, BK=64 staged as two 32-col halves
// (each half keeps the packed [row][32] m97 bank layout), global_load_lds(16).
// If VtOut: column blocks bn >= 2048 (V third of fused QKV) store TRANSPOSED
// to VtOut[(col-2048)][4096].
template <int TM>
__global__ __launch_bounds__(256) void gemm_f16(
    const u16* __restrict__ Af, const u16* __restrict__ Bf,
    const float* __restrict__ bias,
    float* __restrict__ Cf, u16* __restrict__ Cb, int ldc,
    u16* __restrict__ VtOut) {
    constexpr int MI = TM / 32;               // m-subtiles per wave
    __shared__ u16 As[2][TM * 32];
    __shared__ u16 Bs[2][128 * 32];
    const int tid = threadIdx.x;
    const int wid = tid >> 6, lane = tid & 63;
    const int ln = lane & 15, quad = lane >> 4;
    const int bm = blockIdx.y * TM, bn = blockIdx.x * 128;
    const int wm = (wid >> 1) * (TM / 2), wn = (wid & 1) * 64;
    const int lrow = lane >> 2;               // DMA: row within 16-row group
    const int lchunk = (lane & 3) * 8;        // DMA: u16 offset of 16B chunk

    f32x4 acc[MI][4];
#pragma unroll
    for (int i = 0; i < MI; ++i)
#pragma unroll
        for (int j = 0; j < 4; ++j) acc[i][j] = (f32x4){0.f, 0.f, 0.f, 0.f};

    for (int k0 = 0; k0 < 1024; k0 += 64) {
#pragma unroll
        for (int hf = 0; hf < 2; ++hf) {
#pragma unroll
            for (int p = 0; p < TM / 64; ++p) {
                int r = p * 64 + wid * 16;
                glds16(&Af[(bm + r + lrow) * 1024 + k0 + hf * 32 + lchunk],
                       &As[hf][r * 32]);
            }
#pragma unroll
            for (int p = 0; p < 2; ++p) {
                int r = p * 64 + wid * 16;
                glds16(&Bf[(bn + r + lrow) * 1024 + k0 + hf * 32 + lchunk],
                       &Bs[hf][r * 32]);
            }
        }
        asm volatile("s_waitcnt vmcnt(0)" ::: "memory");
        __syncthreads();

        half8 a[MI][2], b[4][2];
#pragma unroll
        for (int kc = 0; kc < 2; ++kc) {
#pragma unroll
            for (int j = 0; j < 4; ++j)
                b[j][kc] = *(const half8*)&Bs[kc][(wn + j * 16 + ln) * 32 + quad * 8];
#pragma unroll
            for (int i = 0; i < MI; ++i)
                a[i][kc] = *(const half8*)&As[kc][(wm + i * 16 + ln) * 32 + quad * 8];
        }
#pragma unroll
        for (int i = 0; i < MI; ++i)
#pragma unroll
            for (int j = 0; j < 4; ++j) {
                acc[i][j] = MFMAH(a[i][0], b[j][0], acc[i][j]);
                acc[i][j] = MFMAH(a[i][1], b[j][1], acc[i][j]);
            }
        __syncthreads();
    }

    if (VtOut && bn >= 2048) {
        // transposed store: VtOut[d][seq]; lane holds 4 consecutive seq rows.
#pragma unroll
        for (int i = 0; i < MI; ++i)
#pragma unroll
            for (int j = 0; j < 4; ++j) {
                int col = bn + wn + j * 16 + ln;
                float bv = bias[col];
                int colV = col - 2048;
                int row0 = bm + wm + i * 16 + quad * 4;
                ushort4 pk = make_ushort4(f2h(acc[i][j][0] + bv), f2h(acc[i][j][1] + bv),
                                          f2h(acc[i][j][2] + bv), f2h(acc[i][j][3] + bv));
                *(ushort4*)&VtOut[colV * 4096 + row0] = pk;
            }
        return;
    }

#pragma unroll
    for (int i = 0; i < MI; ++i)
#pragma unroll
        for (int j = 0; j < 4; ++j) {
            int col = bn + wn + j * 16 + ln;
            float bv = bias[col];
#pragma unroll
            for (int r = 0; r < 4; ++r) {
                int row = bm + wm + i * 16 + quad * 4 + r;
                float v = acc[i][j][r] + bv;
                if (Cb) Cb[row * ldc + col] = f2h(v);
                else    Cf[row * ldc + col] = v;
            }
        }
}

// ============ flash attention, fp16 MFMA, transposed S/O ============
// Block: 4 waves x 32 q-rows = 128 q of one (b,h). 64-key tiles.
// K AND V staged via glds16 (1x traffic) into packed [row][32]-per-half layout
// with XOR chunk swizzle, both-sides -> 0 bank conflicts (verified R4).
// CROSS-TILE PIPELINE (this round): per phase we run
//   stage(kt+2) || QK(kt+1) -> exp/butterfly -> pfNext || PV(kt) with pfCur
// so the next tile's exp VALU chain overlaps the current tile's PV MFMAs
// (independent dataflow, separate pipes, same basic block). K staged 2 ahead,
// V 1 ahead; even/odd phases with named pfA/pfB (static reg indexing); tail
// peeled so the hot loop body is branch-free. Scores in log2 domain ->
// p = v_exp_f32 raw. Row sums via ones-MFMA.
__global__ __launch_bounds__(256) void flash_f16(
    const u16* __restrict__ QKV, const u16* __restrict__ Vt,
    u16* __restrict__ AO) {
    __shared__ u16 Ks[2][2][64 * 32];   // [buf][d-half][key row][32], chunk-swizzled
    __shared__ u16 Vs[2][2][64 * 32];   // [buf][key-half][d row][32], chunk-swizzled

    const int tid = threadIdx.x;
    const int wid = tid >> 6, lane = tid & 63;
    const int ln = lane & 15, quad = lane >> 4;
    const int qt = blockIdx.x, h = blockIdx.y, b = blockIdx.z;
    const int rowbase = b * NQ;
    const int col0 = h * 64;
    const int q0 = rowbase + qt * 128 + wid * 32;
    const int lrow = lane >> 2;          // DMA: row within 16-row group
    // DMA source chunk (pre-swizzle): lane l fetches logical chunk (l&3)^((lrow>>1)&3)
    const int kchunk = ((lane & 3) ^ ((lrow >> 1) & 3)) * 8;
    // fragment-read physical chunk: quad ^ ((row>>1)&3), (row>>1)&3 == (ln>>1)&3
    const int kswz = (quad ^ ((ln >> 1) & 3)) * 8;

    const half8 ones = {(f16)1, (f16)1, (f16)1, (f16)1,
                        (f16)1, (f16)1, (f16)1, (f16)1};

    // Q fragments (B-operand: lane ln = q-row q0+mi*16+ln, k = kc*32+quad*8+j)
    half8 qf[2][2];
#pragma unroll
    for (int mi = 0; mi < 2; ++mi)
#pragma unroll
        for (int kc = 0; kc < 2; ++kc)
            qf[mi][kc] = *(const half8*)&QKV[(q0 + mi * 16 + ln) * 3072 + col0 +
                                             kc * 32 + quad * 8];

    f32x4 accO[4][2];    // [a: d-subtile][mi], element (d=a*16+quad*4+r, q=mi*16+ln)
    f32x4 accS[2];       // row sums, col = q = ln
#pragma unroll
    for (int mi = 0; mi < 2; ++mi) {
        accS[mi] = (f32x4){0.f, 0.f, 0.f, 0.f};
#pragma unroll
        for (int a = 0; a < 4; ++a) accO[a][mi] = (f32x4){0.f, 0.f, 0.f, 0.f};
    }

    const int NT = NQ / 64;
    // DMA per-lane global bases (16 rows x 64B per glds16 call per wave)
    const u16* Kg = QKV + (rowbase + wid * 16 + lrow) * 3072 + 1024 + col0 + kchunk;
    const u16* Vg = Vt + (col0 + wid * 16 + lrow) * 4096 + rowbase + kchunk;

#define STAGEK(kt2, bu)                                        \
    {                                                          \
        const u16* kg_ = Kg + (kt2) * (64 * 3072);             \
        glds16(kg_,      &Ks[bu][0][wid * 512]);               \
        glds16(kg_ + 32, &Ks[bu][1][wid * 512]);               \
    }
#define STAGEV(kt2, bu)                                        \
    {                                                          \
        const u16* vg_ = Vg + (kt2) * 64;                      \
        glds16(vg_,      &Vs[bu][0][wid * 512]);               \
        glds16(vg_ + 32, &Vs[bu][1][wid * 512]);               \
    }

    // QK^T from Ks[kb] -> exp -> butterfly -> pf (B-operand layout) + rowsum.
    auto qk_exp = [&](int kb, half8 (&pf)[2][2]) {
        // S^T = K @ Q^T : element (key = a*16+quad*4+r, q = mi*16+ln)
        f32x4 s[4][2];
#pragma unroll
        for (int a = 0; a < 4; ++a) {
            half8 kf0 = *(const half8*)&Ks[kb][0][(a * 16 + ln) * 32 + kswz];
            half8 kf1 = *(const half8*)&Ks[kb][1][(a * 16 + ln) * 32 + kswz];
#pragma unroll
            for (int mi = 0; mi < 2; ++mi) {
                f32x4 t = (f32x4){0.f, 0.f, 0.f, 0.f};
                t = MFMAH(kf0, qf[mi][0], t);
                t = MFMAH(kf1, qf[mi][1], t);
                s[a][mi] = t;
            }
        }
        // p = 2^s, pack to fp16 pairs, register butterfly to B-operand layout:
        // pf[mi][kc] element j = P[key = kc*32 + quad*8 + j][q = mi*16+ln].
#pragma unroll
        for (int mi = 0; mi < 2; ++mi)
#pragma unroll
            for (int kc = 0; kc < 2; ++kc) {
                u32 c0 = pk_h2(fexp2(s[2 * kc][mi][0]), fexp2(s[2 * kc][mi][1]));
                u32 c1 = pk_h2(fexp2(s[2 * kc][mi][2]), fexp2(s[2 * kc][mi][3]));
                u32 c2 = pk_h2(fexp2(s[2 * kc + 1][mi][0]), fexp2(s[2 * kc + 1][mi][1]));
                u32 c3 = pk_h2(fexp2(s[2 * kc + 1][mi][2]), fexp2(s[2 * kc + 1][mi][3]));
                pl32swap(c0, c2);
                pl32swap(c1, c3);
                pl16swap(c0, c2);
                pl16swap(c1, c3);
                union { u32 u[4]; half8 h; } pu;
                pu.u[0] = c0; pu.u[1] = c1; pu.u[2] = c2; pu.u[3] = c3;
                pf[mi][kc] = pu.h;
                accS[mi] = MFMAH(ones, pf[mi][kc], accS[mi]);   // row sums
            }
    };

    // O^T += V^T @ P^T from Vs[vb] : element (d = a*16+quad*4+r, q = mi*16+ln)
    auto pv = [&](const half8 (&pf)[2][2], int vb) {
#pragma unroll
        for (int a = 0; a < 4; ++a) {
            half8 vf0 = *(const half8*)&Vs[vb][0][(a * 16 + ln) * 32 + kswz];
            half8 vf1 = *(const half8*)&Vs[vb][1][(a * 16 + ln) * 32 + kswz];
#pragma unroll
            for (int mi = 0; mi < 2; ++mi) {
                accO[a][mi] = MFMAH(vf0, pf[mi][0], accO[a][mi]);
                accO[a][mi] = MFMAH(vf1, pf[mi][1], accO[a][mi]);
            }
        }
    };

    half8 pfA[2][2], pfB[2][2];

    // prologue: tile 0 staged, pfA = P(0); K(1) staged for first phase
    STAGEK(0, 0);
    STAGEV(0, 0);
    asm volatile("s_waitcnt vmcnt(0)" ::: "memory");
    __syncthreads();
    STAGEK(1, 1);
    qk_exp(0, pfA);
    asm volatile("s_waitcnt vmcnt(0)" ::: "memory");
    __syncthreads();

    // main loop: branch-free even/odd phases, 2 tiles/iteration.
    // phase A: writes Ks[0],Vs[1]; reads Ks[1](QK kt+1), Vs[0](PV kt).
    // phase B: writes Ks[1],Vs[0]; reads Ks[0](QK kt+2), Vs[1](PV kt+1).
    for (int kt = 0; kt < NT - 2; kt += 2) {
        STAGEK(kt + 2, 0);
        STAGEV(kt + 1, 1);
        qk_exp(1, pfB);          // tile kt+1 (exp overlaps PV below)
        pv(pfA, 0);              // tile kt
        asm volatile("s_waitcnt vmcnt(0)" ::: "memory");
        __syncthreads();

        STAGEK(kt + 3, 1);
        STAGEV(kt + 2, 0);
        qk_exp(0, pfA);          // tile kt+2
        pv(pfB, 1);              // tile kt+1
        asm volatile("s_waitcnt vmcnt(0)" ::: "memory");
        __syncthreads();
    }
    // tail: tiles NT-2, NT-1 (state: pfA = P(NT-2), Ks[1]=K(NT-1), Vs[0]=V(NT-2))
    STAGEV(NT - 1, 1);
    qk_exp(1, pfB);              // tile NT-1
    pv(pfA, 0);                  // tile NT-2
    asm volatile("s_waitcnt vmcnt(0)" ::: "memory");
    __syncthreads();
    pv(pfB, 1);                  // tile NT-1
#undef STAGEK
#undef STAGEV

    // epilogue: normalize (inv uniform per lane), single fp16 AO, ushort4 stores
#pragma unroll
    for (int mi = 0; mi < 2; ++mi) {
        float inv = 1.f / accS[mi][0];
        int q = q0 + mi * 16 + ln;
#pragma unroll
        for (int a = 0; a < 4; ++a) {
            ushort4 pk = make_ushort4(f2h(accO[a][mi][0] * inv),
                                      f2h(accO[a][mi][1] * inv),
                                      f2h(accO[a][mi][2] * inv),
                                      f2h(accO[a][mi][3] * inv));
            *(ushort4*)&AO[q * 1024 + col0 + a * 16 + quad * 4] = pk;
        }
    }
}

// ============ launch ============
extern "C" void kernel_launch(void* const* d_in, const int* in_sizes, int n_in,
                              void* d_out, int out_size, void* d_ws, size_t ws_size,
                              hipStream_t stream) {
    const float* x = (const float*)d_in[0];
    const float* w[4]  = {(const float*)d_in[1],  (const float*)d_in[5],
                          (const float*)d_in[9],  (const float*)d_in[13]};
    const float* bv[4] = {(const float*)d_in[2],  (const float*)d_in[6],
                          (const float*)d_in[10], (const float*)d_in[14]};
    const float* dw[4] = {(const float*)d_in[3],  (const float*)d_in[7],
                          (const float*)d_in[11], (const float*)d_in[15]};
    const float* db[4] = {(const float*)d_in[4],  (const float*)d_in[8],
                          (const float*)d_in[12], (const float*)d_in[16]};

    u16* p = (u16*)d_ws;
    u16* Wf  = p; p += 4096 * 1024;
    u16* xf  = p; p += 4096 * 1024;
    u16* QKV = p; p += 4096 * 3072;   // V third unused (lives in Vt)
    u16* Vt  = p; p += 1024 * 4096;
    float* ball = (float*)p;          // 4096 floats
    // AO aliases xf: x is dead after the QKV GEMM completes (same stream).
    u16* AO = xf;

    merge_w16<<<4096, 256, 0, stream>>>(w[0], dw[0], db[0], w[1], dw[1], db[1],
                                        w[2], dw[2], db[2], w[3], dw[3], db[3], Wf);
    bias_pack<<<16, 256, 0, stream>>>(bv[0], bv[1], bv[2], bv[3], ball);
    xcast<<<4096, 256, 0, stream>>>(x, xf);

    // fused q,k,v projection: q,k -> QKV fp16 row-major; v -> Vt transposed
    gemm_f16<128><<<dim3(24, 32), 256, 0, stream>>>(xf, Wf, ball,
                                                    nullptr, QKV, 3072, Vt);

    flash_f16<<<dim3(NQ / 128, 16, NB), 256, 0, stream>>>(QKV, Vt, AO);

    // o projection: fp32 out, TM=64 -> 512 blocks (2 blocks/CU)
    gemm_f16<64><<<dim3(8, 64), 256, 0, stream>>>(AO, Wf + 3072 * 1024,
                                                  ball + 3072, (float*)d_out, nullptr, 1024,
                                                  nullptr);
}